// Round 1
// baseline (174.717 us; speedup 1.0000x reference)
//
#include <hip/hip_runtime.h>

// PWLU channelwise, fixed bounds. x: [32,256,56,56] f32, points: [256,7] f32.
// out = points[c][r] + (xn - r) * (points[c][r+1] - points[c][r])
//   xn = (x + 2.7)/0.9 ; r = (int)clip(xn, 0, 5)
// HW plane = 3136 elems (divisible by 4) -> float4 chunks are channel-uniform.

#define N_PTS 7
#define VECS_PER_PLANE 784   // 3136 / 4

__global__ __launch_bounds__(256) void pwlu_kernel(
    const float* __restrict__ x,
    const float* __restrict__ points,
    float* __restrict__ out,
    int nvec) {
  int i = blockIdx.x * blockDim.x + threadIdx.x;
  if (i >= nvec) return;

  const float4 xv = reinterpret_cast<const float4*>(x)[i];

  // plane = b*256 + c ; c = plane & 255
  int c = (i / VECS_PER_PLANE) & 255;
  const float* __restrict__ p = points + c * N_PTS;

  float v[4] = {xv.x, xv.y, xv.z, xv.w};
  float r_[4];
#pragma unroll
  for (int k = 0; k < 4; ++k) {
    float xn = (v[k] + 2.7f) * (1.0f / 0.9f);
    float rc = fminf(fmaxf(xn, 0.0f), 5.0f);
    int r = (int)rc;                    // floor (rc >= 0)
    float dist = xn - (float)r;         // uses UNCLIPPED xn per reference
    float lp = p[r];
    float rp = p[r + 1];
    r_[k] = fmaf(dist, rp - lp, lp);
  }

  float4 ov;
  ov.x = r_[0]; ov.y = r_[1]; ov.z = r_[2]; ov.w = r_[3];
  reinterpret_cast<float4*>(out)[i] = ov;
}

extern "C" void kernel_launch(void* const* d_in, const int* in_sizes, int n_in,
                              void* d_out, int out_size, void* d_ws, size_t ws_size,
                              hipStream_t stream) {
  const float* x      = (const float*)d_in[0];
  const float* points = (const float*)d_in[1];
  float* out          = (float*)d_out;

  int n = in_sizes[0];          // 25,690,112 (divisible by 4)
  int nvec = n / 4;             // 6,422,528
  int threads = 256;
  int blocks = (nvec + threads - 1) / threads;
  pwlu_kernel<<<blocks, threads, 0, stream>>>(x, points, out, nvec);
}